// Round 1
// baseline (1735.552 us; speedup 1.0000x reference)
//
#include <hip/hip_runtime.h>
#include <math.h>

#define ZB 4

__device__ __forceinline__ float softsign(float v) {
    float d = 1.0f + fabsf(v);
    return v * __builtin_amdgcn_rcpf(d);
}

__device__ __forceinline__ void load_row6(const float* __restrict__ row, int x0, float r[6]) {
    // row points at x=0 of the (b,z,y) row; x0 is a multiple of 4 in [0,60]
    const float4 v = *(const float4*)(row + x0);
    r[0] = row[x0 == 0 ? 0 : x0 - 1];
    r[1] = v.x; r[2] = v.y; r[3] = v.z; r[4] = v.w;
    r[5] = row[x0 == 60 ? 63 : x0 + 4];
}

__device__ __forceinline__ int clamp63(int v) {
    return v < 0 ? 0 : (v > 63 ? 63 : v);
}

// -------- first layer: 2 input channels (preop, intraop) -> 1 channel --------
__global__ __launch_bounds__(256) void conv_first(const float* __restrict__ in0,
                                                  const float* __restrict__ in1,
                                                  float* __restrict__ out,
                                                  const float* __restrict__ w,   // (1,2,3,3,3) = 54
                                                  const float* __restrict__ bias) {
    int tid = blockIdx.x * 256 + threadIdx.x;
    int xq = (tid & 15) << 2;
    int y  = (tid >> 4) & 63;
    int z0 = ((tid >> 10) & 15) << 2;
    int b  = tid >> 14;
    const float* base0 = in0 + (size_t)b * 262144;
    const float* base1 = in1 + (size_t)b * 262144;

    float acc[ZB][4];
    #pragma unroll
    for (int i = 0; i < ZB; ++i)
        #pragma unroll
        for (int j = 0; j < 4; ++j) acc[i][j] = 0.0f;

    #pragma unroll
    for (int zi = 0; zi < ZB + 2; ++zi) {
        int zin = clamp63(z0 + zi - 1);
        const float* p0 = base0 + zin * 4096;
        const float* p1 = base1 + zin * 4096;
        #pragma unroll
        for (int dy = 0; dy < 3; ++dy) {
            int yin = clamp63(y + dy - 1);
            float r0[6], r1[6];
            load_row6(p0 + yin * 64, xq, r0);
            load_row6(p1 + yin * 64, xq, r1);
            #pragma unroll
            for (int dz = 0; dz < 3; ++dz) {
                int zo = zi - dz;
                if (zo >= 0 && zo < ZB) {
                    #pragma unroll
                    for (int dx = 0; dx < 3; ++dx) {
                        float w0v = w[dz * 9 + dy * 3 + dx];
                        float w1v = w[27 + dz * 9 + dy * 3 + dx];
                        #pragma unroll
                        for (int xx = 0; xx < 4; ++xx) {
                            acc[zo][xx] = fmaf(w0v, r0[xx + dx], acc[zo][xx]);
                            acc[zo][xx] = fmaf(w1v, r1[xx + dx], acc[zo][xx]);
                        }
                    }
                }
            }
        }
    }
    float bv = *bias;
    float* obase = out + (size_t)b * 262144 + (size_t)z0 * 4096 + y * 64 + xq;
    #pragma unroll
    for (int zo = 0; zo < ZB; ++zo) {
        float4 o;
        o.x = softsign(acc[zo][0] + bv);
        o.y = softsign(acc[zo][1] + bv);
        o.z = softsign(acc[zo][2] + bv);
        o.w = softsign(acc[zo][3] + bv);
        *(float4*)(obase + zo * 4096) = o;
    }
}

// -------- middle layers: 1 -> 1 channel --------
__global__ __launch_bounds__(256) void conv_mid(const float* __restrict__ in,
                                                float* __restrict__ out,
                                                const float* __restrict__ w,   // 27
                                                const float* __restrict__ bias) {
    int tid = blockIdx.x * 256 + threadIdx.x;
    int xq = (tid & 15) << 2;
    int y  = (tid >> 4) & 63;
    int z0 = ((tid >> 10) & 15) << 2;
    int b  = tid >> 14;
    const float* base = in + (size_t)b * 262144;

    float acc[ZB][4];
    #pragma unroll
    for (int i = 0; i < ZB; ++i)
        #pragma unroll
        for (int j = 0; j < 4; ++j) acc[i][j] = 0.0f;

    #pragma unroll
    for (int zi = 0; zi < ZB + 2; ++zi) {
        int zin = clamp63(z0 + zi - 1);
        const float* plane = base + zin * 4096;
        #pragma unroll
        for (int dy = 0; dy < 3; ++dy) {
            int yin = clamp63(y + dy - 1);
            float r[6];
            load_row6(plane + yin * 64, xq, r);
            #pragma unroll
            for (int dz = 0; dz < 3; ++dz) {
                int zo = zi - dz;
                if (zo >= 0 && zo < ZB) {
                    #pragma unroll
                    for (int dx = 0; dx < 3; ++dx) {
                        float wv = w[dz * 9 + dy * 3 + dx];
                        #pragma unroll
                        for (int xx = 0; xx < 4; ++xx)
                            acc[zo][xx] = fmaf(wv, r[xx + dx], acc[zo][xx]);
                    }
                }
            }
        }
    }
    float bv = *bias;
    float* obase = out + (size_t)b * 262144 + (size_t)z0 * 4096 + y * 64 + xq;
    #pragma unroll
    for (int zo = 0; zo < ZB; ++zo) {
        float4 o;
        o.x = softsign(acc[zo][0] + bv);
        o.y = softsign(acc[zo][1] + bv);
        o.z = softsign(acc[zo][2] + bv);
        o.w = softsign(acc[zo][3] + bv);
        *(float4*)(obase + zo * 4096) = o;
    }
}

// -------- last layer: 1 -> 3 channels + strided downsample outputs --------
__global__ __launch_bounds__(256) void conv_last(const float* __restrict__ in,
                                                 float* __restrict__ out,
                                                 const float* __restrict__ w,    // (3,1,3,3,3) = 81
                                                 const float* __restrict__ bias) { // 3
    int tid = blockIdx.x * 256 + threadIdx.x;
    int xq = (tid & 15) << 2;
    int y  = (tid >> 4) & 63;
    int z0 = ((tid >> 10) & 15) << 2;
    int b  = tid >> 14;
    const float* base = in + (size_t)b * 262144;

    float acc[ZB][3][4];
    #pragma unroll
    for (int i = 0; i < ZB; ++i)
        #pragma unroll
        for (int c = 0; c < 3; ++c)
            #pragma unroll
            for (int j = 0; j < 4; ++j) acc[i][c][j] = 0.0f;

    #pragma unroll
    for (int zi = 0; zi < ZB + 2; ++zi) {
        int zin = clamp63(z0 + zi - 1);
        const float* plane = base + zin * 4096;
        #pragma unroll
        for (int dy = 0; dy < 3; ++dy) {
            int yin = clamp63(y + dy - 1);
            float r[6];
            load_row6(plane + yin * 64, xq, r);
            #pragma unroll
            for (int dz = 0; dz < 3; ++dz) {
                int zo = zi - dz;
                if (zo >= 0 && zo < ZB) {
                    #pragma unroll
                    for (int c = 0; c < 3; ++c) {
                        #pragma unroll
                        for (int dx = 0; dx < 3; ++dx) {
                            float wv = w[c * 27 + dz * 9 + dy * 3 + dx];
                            #pragma unroll
                            for (int xx = 0; xx < 4; ++xx)
                                acc[zo][c][xx] = fmaf(wv, r[xx + dx], acc[zo][c][xx]);
                        }
                    }
                }
            }
        }
    }

    float* r64 = out;
    float* r32 = out + 12582912;
    float* r16 = r32 + 1572864;
    float* r8  = r16 + 196608;

    float vals[ZB][3][4];
    #pragma unroll
    for (int zo = 0; zo < ZB; ++zo)
        #pragma unroll
        for (int c = 0; c < 3; ++c) {
            float bv = bias[c];
            #pragma unroll
            for (int xx = 0; xx < 4; ++xx)
                vals[zo][c][xx] = softsign(acc[zo][c][xx] + bv);
        }

    // res64
    #pragma unroll
    for (int c = 0; c < 3; ++c) {
        float* cb = r64 + ((size_t)b * 3 + c) * 262144 + (size_t)z0 * 4096 + y * 64 + xq;
        #pragma unroll
        for (int zo = 0; zo < ZB; ++zo) {
            float4 o;
            o.x = vals[zo][c][0]; o.y = vals[zo][c][1];
            o.z = vals[zo][c][2]; o.w = vals[zo][c][3];
            *(float4*)(cb + zo * 4096) = o;
        }
    }
    // res32: even z,y,x.  z0 % 4 == 0 so zo in {0,2}; xq % 4 == 0 so xx in {0,2}
    if ((y & 1) == 0) {
        #pragma unroll
        for (int c = 0; c < 3; ++c) {
            size_t cb = ((size_t)b * 3 + c) * 32768 + (size_t)(y >> 1) * 32;
            #pragma unroll
            for (int zo = 0; zo < ZB; zo += 2) {
                size_t zb = cb + (size_t)((z0 + zo) >> 1) * 1024;
                r32[zb + ((xq + 0) >> 1)] = vals[zo][c][0];
                r32[zb + ((xq + 2) >> 1)] = vals[zo][c][2];
            }
        }
    }
    // res16: z,y,x multiples of 4 -> zo==0, xx==0
    if ((y & 3) == 0) {
        #pragma unroll
        for (int c = 0; c < 3; ++c) {
            r16[((size_t)b * 3 + c) * 4096 + (size_t)(z0 >> 2) * 256 + (y >> 2) * 16 + (xq >> 2)] =
                vals[0][c][0];
        }
    }
    // res8: multiples of 8
    if ((y & 7) == 0 && (z0 & 7) == 0 && (xq & 7) == 0) {
        #pragma unroll
        for (int c = 0; c < 3; ++c) {
            r8[((size_t)b * 3 + c) * 512 + (size_t)(z0 >> 3) * 64 + (y >> 3) * 8 + (xq >> 3)] =
                vals[0][c][0];
        }
    }
}

extern "C" void kernel_launch(void* const* d_in, const int* in_sizes, int n_in,
                              void* d_out, int out_size, void* d_ws, size_t ws_size,
                              hipStream_t stream) {
    const float* preop = (const float*)d_in[0];
    const float* intra = (const float*)d_in[1];
    const float* w0    = (const float*)d_in[2];
    const float* b0    = (const float*)d_in[3];
    const float* ws    = (const float*)d_in[4];
    const float* bs    = (const float*)d_in[5];
    const float* wX    = (const float*)d_in[6];
    const float* bX    = (const float*)d_in[7];
    float* out = (float*)d_out;

    // ping-pong: buf0 in scratch (16.8 MB), buf1 aliased into d_out (rewritten by conv_last)
    float* buf0 = (float*)d_ws;
    float* buf1 = out;

    dim3 grid(1024), block(256);

    conv_first<<<grid, block, 0, stream>>>(preop, intra, buf0, w0, b0);
    for (int i = 0; i < 100; ++i) {
        const float* src = (i & 1) ? buf1 : buf0;
        float* dst       = (i & 1) ? buf0 : buf1;
        conv_mid<<<grid, block, 0, stream>>>(src, dst, ws + i * 27, bs + i);
    }
    // i=99 (odd) wrote buf0 -> final layer reads buf0, writes the real outputs
    conv_last<<<grid, block, 0, stream>>>(buf0, out, wX, bX);
}